// Round 1
// baseline (407.761 us; speedup 1.0000x reference)
//
#include <hip/hip_runtime.h>
#include <hip/hip_bf16.h>
#include <math.h>

// Model: out[b,p,c] = sum_l Kmat[p,l] * x[b,l,c] + bias[p]
// Kmat = Weff_s @ D + (Weff_t - Weff_s) @ (D@T),  Weff = (W @ M)/512
// Output is F32 (resolved r0-r4).
//
// R5 (this round):
//  - xpose: one-time x[b,l,c] f32 -> xT[b,c,l] bf16 (same RNE cvt as before,
//    so MFMA inputs are bit-identical). B-frag becomes ONE b128 global load.
//  - gemm_main_t: XCD-chunked swizzle (6 mt-siblings of each (b,nt) share an
//    XCD's L2 -> x fetched ~once), conflict-free A LDS layout (staged
//    pre-permuted so fragment reads are lane-linear), nontemporal out stores.
//  - build_weff: W tile staged in LDS (was 4 uniform global loads per kk).
//  - Fallback to the verified r4 gemm if ws_size < 73 MB.

#define BATCH 64
#define SEQ 1024
#define CH 512
#define PRED 720
#define INV_SQRT2 0.70710678118654752440f

typedef __attribute__((ext_vector_type(4))) float floatx4;
typedef __attribute__((ext_vector_type(8))) short bf16x8;

// ---- workspace layout (bytes) ----
#define KBF_OFF   0ull          // bf16 Kmat[768][1024]     = 1,572,864 B
#define BIAS_OFF  1572864ull    // f32 bias[768]            =     3,072 B
#define MW_OFF    1575936ull    // f32 Mw[512][512] (M/512) = 1,048,576 B
#define WEFFS_OFF 2624512ull    // f32 WeffS[720][512]      = 1,474,560 B
#define WEFFT_OFF 4099072ull    // f32 WeffT[720][512]      = 1,474,560 B
#define XT_OFF    5573632ull    // bf16 xT[64][512][1024]   = 67,108,864 B
#define WS_NEED   (XT_OFF + 67108864ull)

// ---------------- DCT basis (scale & /512 folded in) ----------------
__global__ void build_M(float* __restrict__ Mw) {
    int idx = blockIdx.x * 256 + threadIdx.x;   // 512*512
    int k = idx >> 9, n = idx & 511;
    int m = ((2 * n + 1) * k) & 2047;
    float ang = (float)m * (float)(M_PI / 1024.0);
    float scale = (k == 0) ? 0.04419417382415922f /* sqrt(1/512) */
                           : 0.0625f;            /* sqrt(2/512)  */
    Mw[idx] = cosf(ang) * scale * (1.0f / 512.0f);
}

// ---------------- Weff = W @ Mw  (720x512 @ 512x512, f32) ----------------
// r5: W rows staged once in LDS (float4, coalesced); inner loop reads are
// LDS broadcasts instead of uniform global loads. Index math unchanged.
__global__ void build_weff(const float* __restrict__ Ws_in, const float* __restrict__ Wt_in,
                           const float* __restrict__ Mw,
                           float* __restrict__ outS, float* __restrict__ outT) {
    const float* W = blockIdx.z ? Wt_in : Ws_in;
    float* out     = blockIdx.z ? outT  : outS;
    int n0 = blockIdx.x * 64;   // 8 tiles
    int p0 = blockIdx.y * 16;   // 45 tiles -> 720
    int t  = threadIdx.x;
    int tn = t & 63, tp = t >> 6;
    int pbase = p0 + tp * 4;
    __shared__ float wt[16][512];   // 32 KB
    __shared__ float mt[64][64];    // 16 KB
    // stage W rows p0..p0+15, full K (2048 float4 quads, 8 per thread)
#pragma unroll
    for (int i = 0; i < 8; i++) {
        int q = i * 256 + t;
        int r = q >> 7, kq4 = q & 127;
        floatx4 v = *reinterpret_cast<const floatx4*>(&W[(size_t)(p0 + r) * 512 + kq4 * 4]);
        *reinterpret_cast<floatx4*>(&wt[r][kq4 * 4]) = v;
    }
    float a0 = 0.f, a1 = 0.f, a2 = 0.f, a3 = 0.f;
    for (int kb = 0; kb < 512; kb += 64) {
        __syncthreads();
        for (int i = 0; i < 16; i++) {
            int idx = t + i * 256;
            mt[idx >> 6][idx & 63] = Mw[(size_t)(kb + (idx >> 6)) * 512 + n0 + (idx & 63)];
        }
        __syncthreads();   // also fences wt staging on first iteration
        for (int kk = 0; kk < 64; kk++) {
            float m = mt[kk][tn];
            int kg = kb + kk;
            a0 += wt[tp * 4 + 0][kg] * m;
            a1 += wt[tp * 4 + 1][kg] * m;
            a2 += wt[tp * 4 + 2][kg] * m;
            a3 += wt[tp * 4 + 3][kg] * m;
        }
    }
    out[(size_t)(pbase + 0) * 512 + n0 + tn] = a0;
    out[(size_t)(pbase + 1) * 512 + n0 + tn] = a1;
    out[(size_t)(pbase + 2) * 512 + n0 + tn] = a2;
    out[(size_t)(pbase + 3) * 512 + n0 + tn] = a3;
}

// ---------------- Kmat build (banded D@T analytic) ----------------
__device__ __forceinline__ int tcnt(int j, int l) {
    if (l == 0)    return max(0, 13 - j);
    if (l == 1023) return max(0, j - 1010);
    int d = l - j; if (d < 0) d = -d;
    return (d <= 12) ? 1 : 0;
}

__global__ void build_kmat(const float* __restrict__ Ws, const float* __restrict__ Wt,
                           const float* __restrict__ bs, const float* __restrict__ bt,
                           __hip_bfloat16* __restrict__ Kbf, float* __restrict__ bias) {
    int idx = blockIdx.x * 256 + threadIdx.x;   // 768*1024
    int p = idx >> 10, l = idx & 1023;
    if (p >= PRED) { Kbf[idx] = __float2bfloat16(0.0f); return; }  // zero pad rows
    if (l == 0) bias[p] = bs[p] + bt[p];
    float v = INV_SQRT2 * Ws[(size_t)p * 512 + (l >> 1)];   // Weff_s @ D term
    int jlo = max(0, l - 12), jhi = min(1023, l + 12);
    float acc = 0.f;
    for (int n = (jlo >> 1); n <= (jhi >> 1); n++) {
        int c = tcnt(2 * n, l) + tcnt(2 * n + 1, l);
        if (c) acc += (Wt[(size_t)p * 512 + n] - Ws[(size_t)p * 512 + n]) * (float)c;
    }
    v += acc * (INV_SQRT2 / 25.0f);
    Kbf[idx] = __float2bfloat16(v);
}

// ---------------- helpers ----------------
__device__ __forceinline__ void async_ld16(const void* g, void* l) {
    __builtin_amdgcn_global_load_lds((const __attribute__((address_space(1))) void*)g,
                                     (__attribute__((address_space(3))) void*)l, 16, 0, 0);
}

__device__ __forceinline__ short f2bf(float f) {
    __hip_bfloat16 h = __float2bfloat16(f);
    return *reinterpret_cast<short*>(&h);
}

// ---------------- xpose: x[b,l,c] f32 -> xT[b,c,l] bf16 ----------------
// 64x64 tiles through padded LDS. Reads coalesced float4 along c; writes
// 16-B bf16x8 runs along l (each 8-lane group = one full 128-B line).
__global__ void __launch_bounds__(256) xpose(const float* __restrict__ x,
                                             short* __restrict__ xT) {
    __shared__ float lds[64][65];
    int t = threadIdx.x;
    int l0 = blockIdx.x * 64, c0 = blockIdx.y * 64, b = blockIdx.z;
    const float* xb = x + (size_t)b * SEQ * CH;
    int row4 = t >> 4, cq = t & 15;
#pragma unroll
    for (int i = 0; i < 4; i++) {
        int row = row4 + i * 16;
        floatx4 v = *reinterpret_cast<const floatx4*>(
            xb + (size_t)(l0 + row) * CH + c0 + cq * 4);
#pragma unroll
        for (int e = 0; e < 4; e++) lds[row][cq * 4 + e] = v[e];
    }
    __syncthreads();
    size_t outb = (size_t)b * CH * SEQ;
#pragma unroll
    for (int r = 0; r < 2; r++) {
        int u = r * 256 + t;
        int lr = u & 7, c = u >> 3;   // c in 0..63
        bf16x8 s;
#pragma unroll
        for (int e = 0; e < 8; e++) s[e] = f2bf(lds[lr * 8 + e][c]);
        *reinterpret_cast<bf16x8*>(&xT[outb + (size_t)(c0 + c) * SEQ + l0 + lr * 8]) = s;
    }
}

// ---------------- main GEMM (transposed-x path) ----------------
// out[b,p,c] = K[p,:] . x[b,:,c] + bias[p]
// A (Kmat bf16) staged via global_load_lds with pre-permuted source so the
// fragment read is lane-linear (conflict-free). B-frag = one b128 load of
// bf16x8 from xT. Grid is XCD-chunk swizzled: the 6 mt-siblings of each
// (b,nt) group land adjacent on one XCD -> x-slice shared in that XCD's L2.
__global__ void __launch_bounds__(256) gemm_main_t(
    const short* __restrict__ Kbf, const short* __restrict__ xT,
    const float* __restrict__ bias, float* __restrict__ out) {
    __shared__ __align__(16) short ldsA[128 * 32];   // 8 KB
    int t = threadIdx.x;
    int wave = t >> 6, lane = t & 63;
    int bid = blockIdx.x;                       // 1536 blocks
    int work = (bid & 7) * 192 + (bid >> 3);    // XCD-chunked, bijective
    int mt = work % 6;                          // mt innermost -> siblings adjacent
    int grp = work / 6;
    int nt = grp & 3, b = grp >> 2;
    int wm = wave >> 1, wn = wave & 1;          // 2x2 waves of 64x64
    int lm = lane & 15, kq = lane >> 4;
    const short* Ag = Kbf + (size_t)mt * 128 * 1024;
    const short* xrow[4];
#pragma unroll
    for (int j = 0; j < 4; j++) {
        int c = nt * 128 + wn * 64 + j * 16 + lm;
        xrow[j] = xT + ((size_t)b * CH + c) * 1024 + kq * 8;
    }

    floatx4 acc[4][4];
#pragma unroll
    for (int i = 0; i < 4; i++)
#pragma unroll
        for (int j = 0; j < 4; j++)
            acc[i][j] = (floatx4){0.f, 0.f, 0.f, 0.f};

    for (int k0 = 0; k0 < 1024; k0 += 32) {
        // stage A tile permuted: LDS 16B slot q holds
        // A[row = (q>>6)*16 + (q&15)][k0 + ((q>>4)&3)*8 .. +8)
        // -> fragment read byte offset = r16*1024 + lane*16 (conflict-free)
#pragma unroll
        for (int rdi = 0; rdi < 2; rdi++) {
            int q = rdi * 256 + t;
            int row = ((q >> 6) << 4) + (q & 15);
            int ko = ((q >> 4) & 3) * 8;
            async_ld16(Ag + (size_t)row * 1024 + k0 + ko,
                       (char*)ldsA + rdi * 4096 + wave * 1024);
        }
        bf16x8 bfrag[4];
#pragma unroll
        for (int j = 0; j < 4; j++)
            bfrag[j] = *reinterpret_cast<const bf16x8*>(xrow[j] + k0);
        __syncthreads();
        bf16x8 af[4];
#pragma unroll
        for (int i = 0; i < 4; i++)
            af[i] = *reinterpret_cast<const bf16x8*>(
                (const char*)ldsA + ((wm * 4 + i) << 10) + (lane << 4));
#pragma unroll
        for (int i = 0; i < 4; i++)
#pragma unroll
            for (int j = 0; j < 4; j++)
                acc[i][j] = __builtin_amdgcn_mfma_f32_16x16x32_bf16(af[i], bfrag[j], acc[i][j], 0, 0, 0);
        __syncthreads();
    }

    // epilogue: D[row=(lane>>4)*4+r][col=lane&15], +bias, nontemporal F32 store
    int p0r = mt * 128 + wm * 64;
    int cb = nt * 128 + wn * 64 + lm;
    size_t outb = (size_t)b * PRED * CH;
#pragma unroll
    for (int i = 0; i < 4; i++) {
#pragma unroll
        for (int r = 0; r < 4; r++) {
            int p = p0r + i * 16 + kq * 4 + r;
            if (p < PRED) {
                float bv = bias[p];
#pragma unroll
                for (int j = 0; j < 4; j++)
                    __builtin_nontemporal_store(acc[i][j][r] + bv,
                                                &out[outb + (size_t)p * CH + cb + j * 16]);
            }
        }
    }
}

// ---------------- fallback GEMM (verified r4 kernel, unchanged) ----------------
__global__ void __launch_bounds__(256) gemm_main(
    const short* __restrict__ Kbf, const float* __restrict__ x,
    const float* __restrict__ bias, float* __restrict__ out) {
    __shared__ __align__(16) short ldsA[128 * 32];   // 8 KB
    int t = threadIdx.x;
    int wave = t >> 6, lane = t & 63;
    int mt = blockIdx.x % 6, nt = blockIdx.x / 6;
    int b  = blockIdx.y;
    int wm = wave >> 1, wn = wave & 1;
    const short* Ag = Kbf + (size_t)mt * 128 * 1024;
    const float* xb = x + (size_t)b * SEQ * CH;
    int lm = lane & 15, kq = lane >> 4;
    int cj[4];
    for (int j = 0; j < 4; j++) cj[j] = nt * 128 + wn * 64 + j * 16 + lm;

    floatx4 acc[4][4];
    for (int i = 0; i < 4; i++)
        for (int j = 0; j < 4; j++)
            acc[i][j] = (floatx4){0.f, 0.f, 0.f, 0.f};

    for (int k0 = 0; k0 < 1024; k0 += 32) {
        for (int rdi = 0; rdi < 2; rdi++) {
            int q = rdi * 256 + t;
            int row = q >> 2, ko = (q & 3) * 8;
            async_ld16(Ag + (size_t)row * 1024 + k0 + ko,
                       (char*)ldsA + rdi * 4096 + wave * 1024);
        }
        bf16x8 bfrag[4];
        int krow = k0 + kq * 8;
#pragma unroll
        for (int j = 0; j < 4; j++) {
            const float* xc = xb + (size_t)krow * CH + cj[j];
            bf16x8 bv;
#pragma unroll
            for (int i = 0; i < 8; i++) bv[i] = f2bf(xc[(size_t)i * CH]);
            bfrag[j] = bv;
        }
        __syncthreads();
        bf16x8 af[4];
        for (int i = 0; i < 4; i++)
            af[i] = *(const bf16x8*)&ldsA[(wm * 64 + i * 16 + lm) * 32 + kq * 8];
        for (int i = 0; i < 4; i++)
            for (int j = 0; j < 4; j++)
                acc[i][j] = __builtin_amdgcn_mfma_f32_16x16x32_bf16(af[i], bfrag[j], acc[i][j], 0, 0, 0);
        __syncthreads();
    }

    int p0 = mt * 128 + wm * 64;
    size_t outb = (size_t)b * PRED * CH;
    for (int i = 0; i < 4; i++) {
        for (int r = 0; r < 4; r++) {
            int p = p0 + i * 16 + kq * 4 + r;
            if (p < PRED) {
                float bv = bias[p];
                for (int j = 0; j < 4; j++) {
                    out[outb + (size_t)p * CH + cj[j]] = acc[i][j][r] + bv;
                }
            }
        }
    }
}

extern "C" void kernel_launch(void* const* d_in, const int* in_sizes, int n_in,
                              void* d_out, int out_size, void* d_ws, size_t ws_size,
                              hipStream_t stream) {
    // size-based remap (robust to order); fallback to dict order
    const float* xp = nullptr; const float* wp[2] = {nullptr, nullptr};
    const float* bp[2] = {nullptr, nullptr};
    int wn = 0, bn = 0;
    for (int i = 0; i < n_in; i++) {
        if (in_sizes[i] == 33554432) xp = (const float*)d_in[i];
        else if (in_sizes[i] == 368640 && wn < 2) wp[wn++] = (const float*)d_in[i];
        else if (in_sizes[i] == 720 && bn < 2) bp[bn++] = (const float*)d_in[i];
    }
    if (!xp || wn != 2 || bn != 2) {
        xp = (const float*)d_in[0]; wp[0] = (const float*)d_in[1];
        bp[0] = (const float*)d_in[2]; wp[1] = (const float*)d_in[3];
        bp[1] = (const float*)d_in[4];
    }
    float* out = (float*)d_out;   // F32 output

    char* ws = (char*)d_ws;
    __hip_bfloat16* Kbf = (__hip_bfloat16*)(ws + KBF_OFF);
    float* bias  = (float*)(ws + BIAS_OFF);
    float* Mw    = (float*)(ws + MW_OFF);
    float* WeffS = (float*)(ws + WEFFS_OFF);
    float* WeffT = (float*)(ws + WEFFT_OFF);
    short* xT    = (short*)(ws + XT_OFF);

    bool big = (ws_size >= (size_t)WS_NEED);

    if (big) xpose<<<dim3(16, 8, 64), 256, 0, stream>>>(xp, xT);
    build_M<<<1024, 256, 0, stream>>>(Mw);
    build_weff<<<dim3(8, 45, 2), 256, 0, stream>>>(wp[0], wp[1], Mw, WeffS, WeffT);
    build_kmat<<<3072, 256, 0, stream>>>(WeffS, WeffT, bp[0], bp[1], Kbf, bias);
    if (big)
        gemm_main_t<<<1536, 256, 0, stream>>>((const short*)Kbf, (const short*)xT, bias, out);
    else
        gemm_main<<<dim3(24, 64), 256, 0, stream>>>((const short*)Kbf, xp, bias, out);
}

// Round 2
// 379.272 us; speedup vs baseline: 1.0751x; 1.0751x over previous
//
#include <hip/hip_runtime.h>
#include <hip/hip_bf16.h>
#include <math.h>

// Model: out[b,p,c] = sum_l Kmat[p,l] * x[b,l,c] + bias[p]
// Kmat = Weff_s @ D + (Weff_t - Weff_s) @ (D@T),  Weff = (W @ M)/512
// Output is F32 (resolved r0-r4).
//
// R6 (this round):
//  - gemm_main_t: 2-phase double-buffered pipeline (catalog T3 minimal
//    recipe). Both A and B staged via global_load_lds into buf[cur^1] BEFORE
//    computing buf[cur]; single barrier per k-step. Removes the per-step
//    vmcnt(0) latency exposure that capped MfmaUtil at 13%. B through LDS
//    also deduplicates the wm-pair B reads (L2 traffic -33%).
//  - build_weff: register-tiled f32 GEMM (4x4 per thread, W^T+M in LDS,
//    2 x ds_read_b128 per 16 FMA). Old version was LDS-issue-bound
//    (5 LDS instr / 4 FMA). Same accumulation order -> bit-identical.
//  - xpose / build_M / build_kmat unchanged (verified r5).

#define BATCH 64
#define SEQ 1024
#define CH 512
#define PRED 720
#define INV_SQRT2 0.70710678118654752440f

typedef __attribute__((ext_vector_type(4))) float floatx4;
typedef __attribute__((ext_vector_type(8))) short bf16x8;

// ---- workspace layout (bytes) ----
#define KBF_OFF   0ull          // bf16 Kmat[768][1024]     = 1,572,864 B
#define BIAS_OFF  1572864ull    // f32 bias[768]            =     3,072 B
#define MW_OFF    1575936ull    // f32 Mw[512][512] (M/512) = 1,048,576 B
#define WEFFS_OFF 2624512ull    // f32 WeffS[720][512]      = 1,474,560 B
#define WEFFT_OFF 4099072ull    // f32 WeffT[720][512]      = 1,474,560 B
#define XT_OFF    5573632ull    // bf16 xT[64][512][1024]   = 67,108,864 B
#define WS_NEED   (XT_OFF + 67108864ull)

// ---------------- DCT basis (scale & /512 folded in) ----------------
__global__ void build_M(float* __restrict__ Mw) {
    int idx = blockIdx.x * 256 + threadIdx.x;   // 512*512
    int k = idx >> 9, n = idx & 511;
    int m = ((2 * n + 1) * k) & 2047;
    float ang = (float)m * (float)(M_PI / 1024.0);
    float scale = (k == 0) ? 0.04419417382415922f /* sqrt(1/512) */
                           : 0.0625f;            /* sqrt(2/512)  */
    Mw[idx] = cosf(ang) * scale * (1.0f / 512.0f);
}

// ---------------- Weff = W @ Mw  (720x512 @ 512x512, f32) ----------------
// R6: register-tiled. Block = 64p x 64n, 256 threads as 16x16, thread = 4x4.
// K chunked by 32: W^T chunk (wlds, padded) + M chunk (mlds) in LDS; inner
// loop = 2 ds_read_b128 (one broadcast, one conflict-free) + 16 FMA per kk.
// Accumulation order (kb asc, kk asc) identical to r5 -> bit-identical Weff.
__global__ void __launch_bounds__(256) build_weff(
    const float* __restrict__ Ws_in, const float* __restrict__ Wt_in,
    const float* __restrict__ Mw,
    float* __restrict__ outS, float* __restrict__ outT) {
    const float* W = blockIdx.z ? Wt_in : Ws_in;
    float* out     = blockIdx.z ? outT  : outS;
    int n0 = blockIdx.x * 64;   // 8 tiles
    int p0 = blockIdx.y * 64;   // 12 tiles (last partial: rows 704..719)
    int t  = threadIdx.x;
    int tx = t & 15, ty = t >> 4;
    __shared__ float wlds[32][65];   // [kk][pp], padded
    __shared__ float mlds[32][64];   // [kk][nn]
    float a[4][4] = {};
    for (int kb = 0; kb < 512; kb += 32) {
        __syncthreads();
        // stage W^T: thread covers row pp = t>>2, k-chunk (t&3)*8 .. +8
        {
            int pp = t >> 2, kk0 = (t & 3) * 8;
            int prow = min(p0 + pp, PRED - 1);   // clamp for partial tile
            const float* wsrc = &W[(size_t)prow * 512 + kb + kk0];
#pragma unroll
            for (int e = 0; e < 8; e++) wlds[kk0 + e][pp] = wsrc[e];
        }
        // stage M: thread covers kk = t>>3, nn-chunk (t&7)*8 .. +8
        {
            int kk = t >> 3, nn = (t & 7) * 8;
            const float* msrc = &Mw[(size_t)(kb + kk) * 512 + n0 + nn];
            *reinterpret_cast<floatx4*>(&mlds[kk][nn])     = *reinterpret_cast<const floatx4*>(&msrc[0]);
            *reinterpret_cast<floatx4*>(&mlds[kk][nn + 4]) = *reinterpret_cast<const floatx4*>(&msrc[4]);
        }
        __syncthreads();
#pragma unroll
        for (int kk = 0; kk < 32; kk++) {
            floatx4 wv = *reinterpret_cast<const floatx4*>(&wlds[kk][ty * 4]);
            floatx4 mv = *reinterpret_cast<const floatx4*>(&mlds[kk][tx * 4]);
#pragma unroll
            for (int i = 0; i < 4; i++)
#pragma unroll
                for (int j = 0; j < 4; j++)
                    a[i][j] += wv[i] * mv[j];
        }
    }
#pragma unroll
    for (int i = 0; i < 4; i++) {
        int p = p0 + ty * 4 + i;
        if (p < PRED) {
            floatx4 v = {a[i][0], a[i][1], a[i][2], a[i][3]};
            *reinterpret_cast<floatx4*>(&out[(size_t)p * 512 + n0 + tx * 4]) = v;
        }
    }
}

// ---------------- Kmat build (banded D@T analytic) ----------------
__device__ __forceinline__ int tcnt(int j, int l) {
    if (l == 0)    return max(0, 13 - j);
    if (l == 1023) return max(0, j - 1010);
    int d = l - j; if (d < 0) d = -d;
    return (d <= 12) ? 1 : 0;
}

__global__ void build_kmat(const float* __restrict__ Ws, const float* __restrict__ Wt,
                           const float* __restrict__ bs, const float* __restrict__ bt,
                           __hip_bfloat16* __restrict__ Kbf, float* __restrict__ bias) {
    int idx = blockIdx.x * 256 + threadIdx.x;   // 768*1024
    int p = idx >> 10, l = idx & 1023;
    if (p >= PRED) { Kbf[idx] = __float2bfloat16(0.0f); return; }  // zero pad rows
    if (l == 0) bias[p] = bs[p] + bt[p];
    float v = INV_SQRT2 * Ws[(size_t)p * 512 + (l >> 1)];   // Weff_s @ D term
    int jlo = max(0, l - 12), jhi = min(1023, l + 12);
    float acc = 0.f;
    for (int n = (jlo >> 1); n <= (jhi >> 1); n++) {
        int c = tcnt(2 * n, l) + tcnt(2 * n + 1, l);
        if (c) acc += (Wt[(size_t)p * 512 + n] - Ws[(size_t)p * 512 + n]) * (float)c;
    }
    v += acc * (INV_SQRT2 / 25.0f);
    Kbf[idx] = __float2bfloat16(v);
}

// ---------------- helpers ----------------
__device__ __forceinline__ void async_ld16(const void* g, void* l) {
    __builtin_amdgcn_global_load_lds((const __attribute__((address_space(1))) void*)g,
                                     (__attribute__((address_space(3))) void*)l, 16, 0, 0);
}

__device__ __forceinline__ short f2bf(float f) {
    __hip_bfloat16 h = __float2bfloat16(f);
    return *reinterpret_cast<short*>(&h);
}

// ---------------- xpose: x[b,l,c] f32 -> xT[b,c,l] bf16 ----------------
__global__ void __launch_bounds__(256) xpose(const float* __restrict__ x,
                                             short* __restrict__ xT) {
    __shared__ float lds[64][65];
    int t = threadIdx.x;
    int l0 = blockIdx.x * 64, c0 = blockIdx.y * 64, b = blockIdx.z;
    const float* xb = x + (size_t)b * SEQ * CH;
    int row4 = t >> 4, cq = t & 15;
#pragma unroll
    for (int i = 0; i < 4; i++) {
        int row = row4 + i * 16;
        floatx4 v = *reinterpret_cast<const floatx4*>(
            xb + (size_t)(l0 + row) * CH + c0 + cq * 4);
#pragma unroll
        for (int e = 0; e < 4; e++) lds[row][cq * 4 + e] = v[e];
    }
    __syncthreads();
    size_t outb = (size_t)b * CH * SEQ;
#pragma unroll
    for (int r = 0; r < 2; r++) {
        int u = r * 256 + t;
        int lr = u & 7, c = u >> 3;   // c in 0..63
        bf16x8 s;
#pragma unroll
        for (int e = 0; e < 8; e++) s[e] = f2bf(lds[lr * 8 + e][c]);
        *reinterpret_cast<bf16x8*>(&xT[outb + (size_t)(c0 + c) * SEQ + l0 + lr * 8]) = s;
    }
}

// ---------------- main GEMM (2-phase double-buffered) ----------------
// out[b,p,c] = K[p,:] . x[b,:,c] + bias[p]
// A and B both staged via global_load_lds with pre-permuted sources so the
// fragment reads are lane-linear (conflict-free). Double-buffered: stage
// tile k+1 into buf^1 BEFORE computing tile k; one barrier per k-step, so
// the barrier's vmcnt(0) drain waits on loads that had the whole
// ds_read+MFMA phase to complete. XCD-chunked grid swizzle as r5.
__global__ void __launch_bounds__(256, 4) gemm_main_t(
    const short* __restrict__ Kbf, const short* __restrict__ xT,
    const float* __restrict__ bias, float* __restrict__ out) {
    // [buf][A|B][128 rows x 32 k] bf16 = 2 * 2 * 8 KB = 32 KB
    __shared__ __align__(16) short ldsbuf[2 * 2 * 128 * 32];
    int t = threadIdx.x;
    int wave = t >> 6, lane = t & 63;
    int bid = blockIdx.x;                       // 1536 blocks
    int work = (bid & 7) * 192 + (bid >> 3);    // XCD-chunked, bijective
    int mt = work % 6;                          // mt innermost -> siblings adjacent
    int grp = work / 6;
    int nt = grp & 3, b = grp >> 2;
    int wm = wave >> 1, wn = wave & 1;          // 2x2 waves of 64x64
    const short* Ag = Kbf + (size_t)mt * 128 * 1024;
    const short* Bg = xT + ((size_t)b * CH + nt * 128) * 1024;

    // per-lane source offsets for permuted staging: chunk q = rdi*256 + t
    // holds row ((q>>6)<<4)+(q&15), k-offset ((q>>4)&3)*8 at LDS slot q*16B.
    size_t srcoff[2];
#pragma unroll
    for (int rdi = 0; rdi < 2; rdi++) {
        int q = rdi * 256 + t;
        int row = ((q >> 6) << 4) + (q & 15);
        int ko = ((q >> 4) & 3) * 8;
        srcoff[rdi] = (size_t)row * 1024 + ko;
    }

    floatx4 acc[4][4];
#pragma unroll
    for (int i = 0; i < 4; i++)
#pragma unroll
        for (int j = 0; j < 4; j++)
            acc[i][j] = (floatx4){0.f, 0.f, 0.f, 0.f};

    // prologue: stage tile 0 into buf 0
#pragma unroll
    for (int rdi = 0; rdi < 2; rdi++) {
        char* dA = (char*)ldsbuf + rdi * 4096 + wave * 1024;
        async_ld16(Ag + srcoff[rdi], dA);
        async_ld16(Bg + srcoff[rdi], dA + 8192);
    }
    __syncthreads();

    int cur = 0;
    for (int it = 0; it < 32; ++it) {
        // stage next tile into buf^1 (skipped on last iteration)
        if (it < 31) {
            int k0n = (it + 1) * 32;
            char* base = (char*)ldsbuf + (cur ^ 1) * 16384;
#pragma unroll
            for (int rdi = 0; rdi < 2; rdi++) {
                char* dA = base + rdi * 4096 + wave * 1024;
                async_ld16(Ag + srcoff[rdi] + k0n, dA);
                async_ld16(Bg + srcoff[rdi] + k0n, dA + 8192);
            }
        }
        // compute current tile
        const char* cb = (const char*)ldsbuf + cur * 16384;
        bf16x8 af[4], bf[4];
#pragma unroll
        for (int i = 0; i < 4; i++)
            af[i] = *reinterpret_cast<const bf16x8*>(cb + ((wm * 4 + i) << 10) + (lane << 4));
#pragma unroll
        for (int j = 0; j < 4; j++)
            bf[j] = *reinterpret_cast<const bf16x8*>(cb + 8192 + ((wn * 4 + j) << 10) + (lane << 4));
#pragma unroll
        for (int i = 0; i < 4; i++)
#pragma unroll
            for (int j = 0; j < 4; j++)
                acc[i][j] = __builtin_amdgcn_mfma_f32_16x16x32_bf16(af[i], bf[j], acc[i][j], 0, 0, 0);
        __syncthreads();   // drains this iter's stage loads + fences LDS reads
        cur ^= 1;
    }

    // epilogue: D[row=(lane>>4)*4+r][col=lane&15], +bias, nontemporal F32 store
    int lm = lane & 15, kq = lane >> 4;
    int p0r = mt * 128 + wm * 64;
    int cb2 = nt * 128 + wn * 64 + lm;
    size_t outb = (size_t)b * PRED * CH;
#pragma unroll
    for (int i = 0; i < 4; i++) {
#pragma unroll
        for (int r = 0; r < 4; r++) {
            int p = p0r + i * 16 + kq * 4 + r;
            if (p < PRED) {
                float bv = bias[p];
#pragma unroll
                for (int j = 0; j < 4; j++)
                    __builtin_nontemporal_store(acc[i][j][r] + bv,
                                                &out[outb + (size_t)p * CH + cb2 + j * 16]);
            }
        }
    }
}

// ---------------- fallback GEMM (verified r4 kernel, unchanged) ----------------
__global__ void __launch_bounds__(256) gemm_main(
    const short* __restrict__ Kbf, const float* __restrict__ x,
    const float* __restrict__ bias, float* __restrict__ out) {
    __shared__ __align__(16) short ldsA[128 * 32];   // 8 KB
    int t = threadIdx.x;
    int wave = t >> 6, lane = t & 63;
    int mt = blockIdx.x % 6, nt = blockIdx.x / 6;
    int b  = blockIdx.y;
    int wm = wave >> 1, wn = wave & 1;
    const short* Ag = Kbf + (size_t)mt * 128 * 1024;
    const float* xb = x + (size_t)b * SEQ * CH;
    int lm = lane & 15, kq = lane >> 4;
    int cj[4];
    for (int j = 0; j < 4; j++) cj[j] = nt * 128 + wn * 64 + j * 16 + lm;

    floatx4 acc[4][4];
    for (int i = 0; i < 4; i++)
        for (int j = 0; j < 4; j++)
            acc[i][j] = (floatx4){0.f, 0.f, 0.f, 0.f};

    for (int k0 = 0; k0 < 1024; k0 += 32) {
        for (int rdi = 0; rdi < 2; rdi++) {
            int q = rdi * 256 + t;
            int row = q >> 2, ko = (q & 3) * 8;
            async_ld16(Ag + (size_t)row * 1024 + k0 + ko,
                       (char*)ldsA + rdi * 4096 + wave * 1024);
        }
        bf16x8 bfrag[4];
        int krow = k0 + kq * 8;
#pragma unroll
        for (int j = 0; j < 4; j++) {
            const float* xc = xb + (size_t)krow * CH + cj[j];
            bf16x8 bv;
#pragma unroll
            for (int i = 0; i < 8; i++) bv[i] = f2bf(xc[(size_t)i * CH]);
            bfrag[j] = bv;
        }
        __syncthreads();
        bf16x8 af[4];
        for (int i = 0; i < 4; i++)
            af[i] = *(const bf16x8*)&ldsA[(wm * 64 + i * 16 + lm) * 32 + kq * 8];
        for (int i = 0; i < 4; i++)
            for (int j = 0; j < 4; j++)
                acc[i][j] = __builtin_amdgcn_mfma_f32_16x16x32_bf16(af[i], bfrag[j], acc[i][j], 0, 0, 0);
        __syncthreads();
    }

    int p0 = mt * 128 + wm * 64;
    size_t outb = (size_t)b * PRED * CH;
    for (int i = 0; i < 4; i++) {
        for (int r = 0; r < 4; r++) {
            int p = p0 + i * 16 + kq * 4 + r;
            if (p < PRED) {
                float bv = bias[p];
                for (int j = 0; j < 4; j++) {
                    out[outb + (size_t)p * CH + cj[j]] = acc[i][j][r] + bv;
                }
            }
        }
    }
}

extern "C" void kernel_launch(void* const* d_in, const int* in_sizes, int n_in,
                              void* d_out, int out_size, void* d_ws, size_t ws_size,
                              hipStream_t stream) {
    // size-based remap (robust to order); fallback to dict order
    const float* xp = nullptr; const float* wp[2] = {nullptr, nullptr};
    const float* bp[2] = {nullptr, nullptr};
    int wn = 0, bn = 0;
    for (int i = 0; i < n_in; i++) {
        if (in_sizes[i] == 33554432) xp = (const float*)d_in[i];
        else if (in_sizes[i] == 368640 && wn < 2) wp[wn++] = (const float*)d_in[i];
        else if (in_sizes[i] == 720 && bn < 2) bp[bn++] = (const float*)d_in[i];
    }
    if (!xp || wn != 2 || bn != 2) {
        xp = (const float*)d_in[0]; wp[0] = (const float*)d_in[1];
        bp[0] = (const float*)d_in[2]; wp[1] = (const float*)d_in[3];
        bp[1] = (const float*)d_in[4];
    }
    float* out = (float*)d_out;   // F32 output

    char* ws = (char*)d_ws;
    __hip_bfloat16* Kbf = (__hip_bfloat16*)(ws + KBF_OFF);
    float* bias  = (float*)(ws + BIAS_OFF);
    float* Mw    = (float*)(ws + MW_OFF);
    float* WeffS = (float*)(ws + WEFFS_OFF);
    float* WeffT = (float*)(ws + WEFFT_OFF);
    short* xT    = (short*)(ws + XT_OFF);

    bool big = (ws_size >= (size_t)WS_NEED);

    if (big) xpose<<<dim3(16, 8, 64), 256, 0, stream>>>(xp, xT);
    build_M<<<1024, 256, 0, stream>>>(Mw);
    build_weff<<<dim3(8, 12, 2), 256, 0, stream>>>(wp[0], wp[1], Mw, WeffS, WeffT);
    build_kmat<<<3072, 256, 0, stream>>>(WeffS, WeffT, bp[0], bp[1], Kbf, bias);
    if (big)
        gemm_main_t<<<1536, 256, 0, stream>>>((const short*)Kbf, (const short*)xT, bias, out);
    else
        gemm_main<<<dim3(24, 64), 256, 0, stream>>>((const short*)Kbf, xp, bias, out);
}

// Round 3
// 367.958 us; speedup vs baseline: 1.1082x; 1.0307x over previous
//
#include <hip/hip_runtime.h>
#include <hip/hip_bf16.h>
#include <math.h>

// Model: out[b,p,c] = sum_l Kmat[p,l] * x[b,l,c] + bias[p]
// Kmat = Weff_s @ D + (Weff_t - Weff_s) @ (D@T),  Weff = (W @ M)/512
// Output is F32 (resolved r0-r4).
//
// R7 (this round):
//  - gemm_main_t: depth-2 software pipeline (catalog T4). 3 LDS buffers,
//    raw s_barrier + counted "s_waitcnt vmcnt(4)" so the newest stage's
//    loads stay in flight across the barrier (the 2-phase __syncthreads
//    drained vmcnt(0) every k-step -> 17% MfmaUtil latency bound).
//    sched_barrier(0) after each barrier pins the next stage issue AFTER
//    the barrier (buffer-reuse safety: stage(it+2) overwrites buf[(it-1)%3],
//    whose reads all waves finished before barrier(it)). setprio around the
//    MFMA cluster (T5 rider). Math order & layouts identical to verified R6.
//  - xpose: nontemporal x loads (x read exactly once; keep L3 for xT).
//  - build_weff/build_M/build_kmat unchanged (verified r6).

#define BATCH 64
#define SEQ 1024
#define CH 512
#define PRED 720
#define INV_SQRT2 0.70710678118654752440f

typedef __attribute__((ext_vector_type(4))) float floatx4;
typedef __attribute__((ext_vector_type(8))) short bf16x8;

// ---- workspace layout (bytes) ----
#define KBF_OFF   0ull          // bf16 Kmat[768][1024]     = 1,572,864 B
#define BIAS_OFF  1572864ull    // f32 bias[768]            =     3,072 B
#define MW_OFF    1575936ull    // f32 Mw[512][512] (M/512) = 1,048,576 B
#define WEFFS_OFF 2624512ull    // f32 WeffS[720][512]      = 1,474,560 B
#define WEFFT_OFF 4099072ull    // f32 WeffT[720][512]      = 1,474,560 B
#define XT_OFF    5573632ull    // bf16 xT[64][512][1024]   = 67,108,864 B
#define WS_NEED   (XT_OFF + 67108864ull)

// ---------------- DCT basis (scale & /512 folded in) ----------------
__global__ void build_M(float* __restrict__ Mw) {
    int idx = blockIdx.x * 256 + threadIdx.x;   // 512*512
    int k = idx >> 9, n = idx & 511;
    int m = ((2 * n + 1) * k) & 2047;
    float ang = (float)m * (float)(M_PI / 1024.0);
    float scale = (k == 0) ? 0.04419417382415922f /* sqrt(1/512) */
                           : 0.0625f;            /* sqrt(2/512)  */
    Mw[idx] = cosf(ang) * scale * (1.0f / 512.0f);
}

// ---------------- Weff = W @ Mw  (720x512 @ 512x512, f32) ----------------
// Register-tiled (verified r6). Block = 64p x 64n, thread = 4x4.
__global__ void __launch_bounds__(256) build_weff(
    const float* __restrict__ Ws_in, const float* __restrict__ Wt_in,
    const float* __restrict__ Mw,
    float* __restrict__ outS, float* __restrict__ outT) {
    const float* W = blockIdx.z ? Wt_in : Ws_in;
    float* out     = blockIdx.z ? outT  : outS;
    int n0 = blockIdx.x * 64;   // 8 tiles
    int p0 = blockIdx.y * 64;   // 12 tiles (last partial: rows 704..719)
    int t  = threadIdx.x;
    int tx = t & 15, ty = t >> 4;
    __shared__ float wlds[32][65];   // [kk][pp], padded
    __shared__ float mlds[32][64];   // [kk][nn]
    float a[4][4] = {};
    for (int kb = 0; kb < 512; kb += 32) {
        __syncthreads();
        {
            int pp = t >> 2, kk0 = (t & 3) * 8;
            int prow = min(p0 + pp, PRED - 1);   // clamp for partial tile
            const float* wsrc = &W[(size_t)prow * 512 + kb + kk0];
#pragma unroll
            for (int e = 0; e < 8; e++) wlds[kk0 + e][pp] = wsrc[e];
        }
        {
            int kk = t >> 3, nn = (t & 7) * 8;
            const float* msrc = &Mw[(size_t)(kb + kk) * 512 + n0 + nn];
            *reinterpret_cast<floatx4*>(&mlds[kk][nn])     = *reinterpret_cast<const floatx4*>(&msrc[0]);
            *reinterpret_cast<floatx4*>(&mlds[kk][nn + 4]) = *reinterpret_cast<const floatx4*>(&msrc[4]);
        }
        __syncthreads();
#pragma unroll
        for (int kk = 0; kk < 32; kk++) {
            floatx4 wv = *reinterpret_cast<const floatx4*>(&wlds[kk][ty * 4]);
            floatx4 mv = *reinterpret_cast<const floatx4*>(&mlds[kk][tx * 4]);
#pragma unroll
            for (int i = 0; i < 4; i++)
#pragma unroll
                for (int j = 0; j < 4; j++)
                    a[i][j] += wv[i] * mv[j];
        }
    }
#pragma unroll
    for (int i = 0; i < 4; i++) {
        int p = p0 + ty * 4 + i;
        if (p < PRED) {
            floatx4 v = {a[i][0], a[i][1], a[i][2], a[i][3]};
            *reinterpret_cast<floatx4*>(&out[(size_t)p * 512 + n0 + tx * 4]) = v;
        }
    }
}

// ---------------- Kmat build (banded D@T analytic) ----------------
__device__ __forceinline__ int tcnt(int j, int l) {
    if (l == 0)    return max(0, 13 - j);
    if (l == 1023) return max(0, j - 1010);
    int d = l - j; if (d < 0) d = -d;
    return (d <= 12) ? 1 : 0;
}

__global__ void build_kmat(const float* __restrict__ Ws, const float* __restrict__ Wt,
                           const float* __restrict__ bs, const float* __restrict__ bt,
                           __hip_bfloat16* __restrict__ Kbf, float* __restrict__ bias) {
    int idx = blockIdx.x * 256 + threadIdx.x;   // 768*1024
    int p = idx >> 10, l = idx & 1023;
    if (p >= PRED) { Kbf[idx] = __float2bfloat16(0.0f); return; }  // zero pad rows
    if (l == 0) bias[p] = bs[p] + bt[p];
    float v = INV_SQRT2 * Ws[(size_t)p * 512 + (l >> 1)];   // Weff_s @ D term
    int jlo = max(0, l - 12), jhi = min(1023, l + 12);
    float acc = 0.f;
    for (int n = (jlo >> 1); n <= (jhi >> 1); n++) {
        int c = tcnt(2 * n, l) + tcnt(2 * n + 1, l);
        if (c) acc += (Wt[(size_t)p * 512 + n] - Ws[(size_t)p * 512 + n]) * (float)c;
    }
    v += acc * (INV_SQRT2 / 25.0f);
    Kbf[idx] = __float2bfloat16(v);
}

// ---------------- helpers ----------------
__device__ __forceinline__ void async_ld16(const void* g, void* l) {
    __builtin_amdgcn_global_load_lds((const __attribute__((address_space(1))) void*)g,
                                     (__attribute__((address_space(3))) void*)l, 16, 0, 0);
}

__device__ __forceinline__ short f2bf(float f) {
    __hip_bfloat16 h = __float2bfloat16(f);
    return *reinterpret_cast<short*>(&h);
}

// ---------------- xpose: x[b,l,c] f32 -> xT[b,c,l] bf16 ----------------
__global__ void __launch_bounds__(256) xpose(const float* __restrict__ x,
                                             short* __restrict__ xT) {
    __shared__ float lds[64][65];
    int t = threadIdx.x;
    int l0 = blockIdx.x * 64, c0 = blockIdx.y * 64, b = blockIdx.z;
    const float* xb = x + (size_t)b * SEQ * CH;
    int row4 = t >> 4, cq = t & 15;
#pragma unroll
    for (int i = 0; i < 4; i++) {
        int row = row4 + i * 16;
        floatx4 v = __builtin_nontemporal_load(reinterpret_cast<const floatx4*>(
            xb + (size_t)(l0 + row) * CH + c0 + cq * 4));
#pragma unroll
        for (int e = 0; e < 4; e++) lds[row][cq * 4 + e] = v[e];
    }
    __syncthreads();
    size_t outb = (size_t)b * CH * SEQ;
#pragma unroll
    for (int r = 0; r < 2; r++) {
        int u = r * 256 + t;
        int lr = u & 7, c = u >> 3;   // c in 0..63
        bf16x8 s;
#pragma unroll
        for (int e = 0; e < 8; e++) s[e] = f2bf(lds[lr * 8 + e][c]);
        *reinterpret_cast<bf16x8*>(&xT[outb + (size_t)(c0 + c) * SEQ + l0 + lr * 8]) = s;
    }
}

// ---------------- main GEMM (depth-2 pipeline, counted vmcnt) ----------------
// out[b,p,c] = K[p,:] . x[b,:,c] + bias[p]
// 3 LDS buffers; stage(it+2) issued right after barrier(it); vmcnt(4) at the
// barrier leaves the newest stage in flight. Buffer-reuse safety: stage(it+2)
// targets buf[(it+2)%3] == buf[(it-1)%3]; every wave finished its ds_reads of
// that buffer before reaching barrier(it) (lgkm waits precede the MFMAs that
// consumed them), so post-barrier writes cannot race.
__global__ void __launch_bounds__(256, 3) gemm_main_t(
    const short* __restrict__ Kbf, const short* __restrict__ xT,
    const float* __restrict__ bias, float* __restrict__ out) {
    // [buf 0..2][A|B][128 rows x 32 k] bf16 = 3 * 16 KB = 48 KB
    __shared__ __align__(16) short ldsbuf[3 * 2 * 128 * 32];
    int t = threadIdx.x;
    int wave = t >> 6, lane = t & 63;
    int bid = blockIdx.x;                       // 1536 blocks
    int work = (bid & 7) * 192 + (bid >> 3);    // XCD-chunked, bijective
    int mt = work % 6;                          // mt innermost -> siblings adjacent
    int grp = work / 6;
    int nt = grp & 3, b = grp >> 2;
    int wm = wave >> 1, wn = wave & 1;          // 2x2 waves of 64x64
    const short* Ag = Kbf + (size_t)mt * 128 * 1024;
    const short* Bg = xT + ((size_t)b * CH + nt * 128) * 1024;

    // per-lane source offsets for permuted staging: chunk q = rdi*256 + t
    // holds row ((q>>6)<<4)+(q&15), k-offset ((q>>4)&3)*8 at LDS slot q*16B.
    size_t srcoff[2];
#pragma unroll
    for (int rdi = 0; rdi < 2; rdi++) {
        int q = rdi * 256 + t;
        int row = ((q >> 6) << 4) + (q & 15);
        int ko = ((q >> 4) & 3) * 8;
        srcoff[rdi] = (size_t)row * 1024 + ko;
    }

    floatx4 acc[4][4];
#pragma unroll
    for (int i = 0; i < 4; i++)
#pragma unroll
        for (int j = 0; j < 4; j++)
            acc[i][j] = (floatx4){0.f, 0.f, 0.f, 0.f};

    // prologue: stage tiles 0,1 into bufs 0,1  (4 loads per thread per stage)
#pragma unroll
    for (int s = 0; s < 2; s++) {
        char* base = (char*)ldsbuf + s * 16384;
        int k0 = s * 32;
#pragma unroll
        for (int rdi = 0; rdi < 2; rdi++) {
            char* dA = base + rdi * 4096 + wave * 1024;
            async_ld16(Ag + srcoff[rdi] + k0, dA);
            async_ld16(Bg + srcoff[rdi] + k0, dA + 8192);
        }
    }

    int cur = 0, nx2 = 2;
    for (int it = 0; it < 31; ++it) {
        // tile it's 4 loads are older than the newest 4 (stage it+1) -> done.
        asm volatile("s_waitcnt vmcnt(4)" ::: "memory");
        __builtin_amdgcn_s_barrier();
        __builtin_amdgcn_sched_barrier(0);   // pin stage issue AFTER barrier
        if (it < 30) {
            int k0n = (it + 2) * 32;
            char* base = (char*)ldsbuf + nx2 * 16384;
#pragma unroll
            for (int rdi = 0; rdi < 2; rdi++) {
                char* dA = base + rdi * 4096 + wave * 1024;
                async_ld16(Ag + srcoff[rdi] + k0n, dA);
                async_ld16(Bg + srcoff[rdi] + k0n, dA + 8192);
            }
        }
        const char* cb = (const char*)ldsbuf + cur * 16384;
        bf16x8 af[4], bf[4];
#pragma unroll
        for (int i = 0; i < 4; i++)
            af[i] = *reinterpret_cast<const bf16x8*>(cb + ((wm * 4 + i) << 10) + (lane << 4));
#pragma unroll
        for (int j = 0; j < 4; j++)
            bf[j] = *reinterpret_cast<const bf16x8*>(cb + 8192 + ((wn * 4 + j) << 10) + (lane << 4));
        __builtin_amdgcn_s_setprio(1);
#pragma unroll
        for (int i = 0; i < 4; i++)
#pragma unroll
            for (int j = 0; j < 4; j++)
                acc[i][j] = __builtin_amdgcn_mfma_f32_16x16x32_bf16(af[i], bf[j], acc[i][j], 0, 0, 0);
        __builtin_amdgcn_s_setprio(0);
        cur = (cur == 2) ? 0 : cur + 1;
        nx2 = (nx2 == 2) ? 0 : nx2 + 1;
    }
    // peeled last tile (it = 31): everything must be in.
    asm volatile("s_waitcnt vmcnt(0)" ::: "memory");
    __builtin_amdgcn_s_barrier();
    __builtin_amdgcn_sched_barrier(0);
    {
        const char* cb = (const char*)ldsbuf + cur * 16384;
        bf16x8 af[4], bf[4];
#pragma unroll
        for (int i = 0; i < 4; i++)
            af[i] = *reinterpret_cast<const bf16x8*>(cb + ((wm * 4 + i) << 10) + (lane << 4));
#pragma unroll
        for (int j = 0; j < 4; j++)
            bf[j] = *reinterpret_cast<const bf16x8*>(cb + 8192 + ((wn * 4 + j) << 10) + (lane << 4));
#pragma unroll
        for (int i = 0; i < 4; i++)
#pragma unroll
            for (int j = 0; j < 4; j++)
                acc[i][j] = __builtin_amdgcn_mfma_f32_16x16x32_bf16(af[i], bf[j], acc[i][j], 0, 0, 0);
    }

    // epilogue: D[row=(lane>>4)*4+r][col=lane&15], +bias, nontemporal F32 store
    int lm = lane & 15, kq = lane >> 4;
    int p0r = mt * 128 + wm * 64;
    int cb2 = nt * 128 + wn * 64 + lm;
    size_t outb = (size_t)b * PRED * CH;
#pragma unroll
    for (int i = 0; i < 4; i++) {
#pragma unroll
        for (int r = 0; r < 4; r++) {
            int p = p0r + i * 16 + kq * 4 + r;
            if (p < PRED) {
                float bv = bias[p];
#pragma unroll
                for (int j = 0; j < 4; j++)
                    __builtin_nontemporal_store(acc[i][j][r] + bv,
                                                &out[outb + (size_t)p * CH + cb2 + j * 16]);
            }
        }
    }
}

// ---------------- fallback GEMM (verified r4 kernel, unchanged) ----------------
__global__ void __launch_bounds__(256) gemm_main(
    const short* __restrict__ Kbf, const float* __restrict__ x,
    const float* __restrict__ bias, float* __restrict__ out) {
    __shared__ __align__(16) short ldsA[128 * 32];   // 8 KB
    int t = threadIdx.x;
    int wave = t >> 6, lane = t & 63;
    int mt = blockIdx.x % 6, nt = blockIdx.x / 6;
    int b  = blockIdx.y;
    int wm = wave >> 1, wn = wave & 1;
    const short* Ag = Kbf + (size_t)mt * 128 * 1024;
    const float* xb = x + (size_t)b * SEQ * CH;
    int lm = lane & 15, kq = lane >> 4;
    int cj[4];
    for (int j = 0; j < 4; j++) cj[j] = nt * 128 + wn * 64 + j * 16 + lm;

    floatx4 acc[4][4];
    for (int i = 0; i < 4; i++)
        for (int j = 0; j < 4; j++)
            acc[i][j] = (floatx4){0.f, 0.f, 0.f, 0.f};

    for (int k0 = 0; k0 < 1024; k0 += 32) {
        for (int rdi = 0; rdi < 2; rdi++) {
            int q = rdi * 256 + t;
            int row = q >> 2, ko = (q & 3) * 8;
            async_ld16(Ag + (size_t)row * 1024 + k0 + ko,
                       (char*)ldsA + rdi * 4096 + wave * 1024);
        }
        bf16x8 bfrag[4];
        int krow = k0 + kq * 8;
#pragma unroll
        for (int j = 0; j < 4; j++) {
            const float* xc = xb + (size_t)krow * CH + cj[j];
            bf16x8 bv;
#pragma unroll
            for (int i = 0; i < 8; i++) bv[i] = f2bf(xc[(size_t)i * CH]);
            bfrag[j] = bv;
        }
        __syncthreads();
        bf16x8 af[4];
        for (int i = 0; i < 4; i++)
            af[i] = *(const bf16x8*)&ldsA[(wm * 64 + i * 16 + lm) * 32 + kq * 8];
        for (int i = 0; i < 4; i++)
            for (int j = 0; j < 4; j++)
                acc[i][j] = __builtin_amdgcn_mfma_f32_16x16x32_bf16(af[i], bfrag[j], acc[i][j], 0, 0, 0);
        __syncthreads();
    }

    int p0 = mt * 128 + wm * 64;
    size_t outb = (size_t)b * PRED * CH;
    for (int i = 0; i < 4; i++) {
        for (int r = 0; r < 4; r++) {
            int p = p0 + i * 16 + kq * 4 + r;
            if (p < PRED) {
                float bv = bias[p];
                for (int j = 0; j < 4; j++) {
                    out[outb + (size_t)p * CH + cj[j]] = acc[i][j][r] + bv;
                }
            }
        }
    }
}

extern "C" void kernel_launch(void* const* d_in, const int* in_sizes, int n_in,
                              void* d_out, int out_size, void* d_ws, size_t ws_size,
                              hipStream_t stream) {
    // size-based remap (robust to order); fallback to dict order
    const float* xp = nullptr; const float* wp[2] = {nullptr, nullptr};
    const float* bp[2] = {nullptr, nullptr};
    int wn = 0, bn = 0;
    for (int i = 0; i < n_in; i++) {
        if (in_sizes[i] == 33554432) xp = (const float*)d_in[i];
        else if (in_sizes[i] == 368640 && wn < 2) wp[wn++] = (const float*)d_in[i];
        else if (in_sizes[i] == 720 && bn < 2) bp[bn++] = (const float*)d_in[i];
    }
    if (!xp || wn != 2 || bn != 2) {
        xp = (const float*)d_in[0]; wp[0] = (const float*)d_in[1];
        bp[0] = (const float*)d_in[2]; wp[1] = (const float*)d_in[3];
        bp[1] = (const float*)d_in[4];
    }
    float* out = (float*)d_out;   // F32 output

    char* ws = (char*)d_ws;
    __hip_bfloat16* Kbf = (__hip_bfloat16*)(ws + KBF_OFF);
    float* bias  = (float*)(ws + BIAS_OFF);
    float* Mw    = (float*)(ws + MW_OFF);
    float* WeffS = (float*)(ws + WEFFS_OFF);
    float* WeffT = (float*)(ws + WEFFT_OFF);
    short* xT    = (short*)(ws + XT_OFF);

    bool big = (ws_size >= (size_t)WS_NEED);

    if (big) xpose<<<dim3(16, 8, 64), 256, 0, stream>>>(xp, xT);
    build_M<<<1024, 256, 0, stream>>>(Mw);
    build_weff<<<dim3(8, 12, 2), 256, 0, stream>>>(wp[0], wp[1], Mw, WeffS, WeffT);
    build_kmat<<<3072, 256, 0, stream>>>(WeffS, WeffT, bp[0], bp[1], Kbf, bias);
    if (big)
        gemm_main_t<<<1536, 256, 0, stream>>>((const short*)Kbf, (const short*)xT, bias, out);
    else
        gemm_main<<<dim3(24, 64), 256, 0, stream>>>((const short*)Kbf, xp, bias, out);
}

// Round 4
// 349.652 us; speedup vs baseline: 1.1662x; 1.0524x over previous
//
#include <hip/hip_runtime.h>
#include <hip/hip_bf16.h>
#include <math.h>

// Model: out[b,p,c] = sum_l Kmat[p,l] * x[b,l,c] + bias[p]
// Kmat = Weff_s @ D + (Weff_t - Weff_s) @ (D@T),  Weff = (W @ M)/512
// Output is F32 (resolved r0-r4).
//
// R8 (this round):
//  - gemm_main_t: scale the verified R7 3-buffer depth-2 counted-vmcnt
//    pipeline to BM=128 x BN=256 x BK=64, 512 threads (8 waves, 2x4).
//    4x MFMA per barrier interval (R7's 20% MfmaUtil was barrier-interval
//    latency, not pipeline depth). Batched N flattened: n = b*512+c ->
//    grid 6x128 = 768 blocks = exactly 3 generations at 1 block/CU
//    (144 KB LDS). vmcnt(6) (6 loads/thread/stage). Same k-order ->
//    bit-identical output.
//  - build_weff: Mw computed inline while staging (bit-identical values);
//    build_M kernel and its launch removed.
//  - xpose / build_kmat unchanged (verified).

#define BATCH 64
#define SEQ 1024
#define CH 512
#define PRED 720
#define INV_SQRT2 0.70710678118654752440f

typedef __attribute__((ext_vector_type(4))) float floatx4;
typedef __attribute__((ext_vector_type(8))) short bf16x8;

// ---- workspace layout (bytes) ----
#define KBF_OFF   0ull          // bf16 Kmat[768][1024]     = 1,572,864 B
#define BIAS_OFF  1572864ull    // f32 bias[768]            =     3,072 B
#define MW_OFF    1575936ull    // (unused since R8)
#define WEFFS_OFF 2624512ull    // f32 WeffS[720][512]      = 1,474,560 B
#define WEFFT_OFF 4099072ull    // f32 WeffT[720][512]      = 1,474,560 B
#define XT_OFF    5573632ull    // bf16 xT[64][512][1024]   = 67,108,864 B
#define WS_NEED   (XT_OFF + 67108864ull)

// ---------------- Weff = W @ M/512  (720x512 @ 512x512, f32) ----------------
// Register-tiled (verified r6). Block = 64p x 64n, thread = 4x4.
// R8: M tile computed inline (same formula as the old build_M -> bit-identical).
__global__ void __launch_bounds__(256) build_weff(
    const float* __restrict__ Ws_in, const float* __restrict__ Wt_in,
    float* __restrict__ outS, float* __restrict__ outT) {
    const float* W = blockIdx.z ? Wt_in : Ws_in;
    float* out     = blockIdx.z ? outT  : outS;
    int n0 = blockIdx.x * 64;   // 8 tiles
    int p0 = blockIdx.y * 64;   // 12 tiles (last partial: rows 704..719)
    int t  = threadIdx.x;
    int tx = t & 15, ty = t >> 4;
    __shared__ float wlds[32][65];   // [kk][pp], padded
    __shared__ float mlds[32][64];   // [kk][nn]
    float a[4][4] = {};
    for (int kb = 0; kb < 512; kb += 32) {
        __syncthreads();
        {
            int pp = t >> 2, kk0 = (t & 3) * 8;
            int prow = min(p0 + pp, PRED - 1);   // clamp for partial tile
            const float* wsrc = &W[(size_t)prow * 512 + kb + kk0];
#pragma unroll
            for (int e = 0; e < 8; e++) wlds[kk0 + e][pp] = wsrc[e];
        }
        {
            // inline DCT basis: Mw[k][n] = cos(pi*((2n+1)k mod 2048)/1024)*scale/512
            int kk = t >> 3, nn0 = (t & 7) * 8;
            int k = kb + kk;
            float scale = (k == 0) ? 0.04419417382415922f /* sqrt(1/512) */
                                   : 0.0625f;              /* sqrt(2/512)  */
            scale *= (1.0f / 512.0f);
#pragma unroll
            for (int e = 0; e < 8; e++) {
                int n = n0 + nn0 + e;
                int m = ((2 * n + 1) * k) & 2047;
                float ang = (float)m * (float)(M_PI / 1024.0);
                mlds[kk][nn0 + e] = cosf(ang) * scale;
            }
        }
        __syncthreads();
#pragma unroll
        for (int kk = 0; kk < 32; kk++) {
            floatx4 wv = *reinterpret_cast<const floatx4*>(&wlds[kk][ty * 4]);
            floatx4 mv = *reinterpret_cast<const floatx4*>(&mlds[kk][tx * 4]);
#pragma unroll
            for (int i = 0; i < 4; i++)
#pragma unroll
                for (int j = 0; j < 4; j++)
                    a[i][j] += wv[i] * mv[j];
        }
    }
#pragma unroll
    for (int i = 0; i < 4; i++) {
        int p = p0 + ty * 4 + i;
        if (p < PRED) {
            floatx4 v = {a[i][0], a[i][1], a[i][2], a[i][3]};
            *reinterpret_cast<floatx4*>(&out[(size_t)p * 512 + n0 + tx * 4]) = v;
        }
    }
}

// ---------------- Kmat build (banded D@T analytic) ----------------
__device__ __forceinline__ int tcnt(int j, int l) {
    if (l == 0)    return max(0, 13 - j);
    if (l == 1023) return max(0, j - 1010);
    int d = l - j; if (d < 0) d = -d;
    return (d <= 12) ? 1 : 0;
}

__global__ void build_kmat(const float* __restrict__ Ws, const float* __restrict__ Wt,
                           const float* __restrict__ bs, const float* __restrict__ bt,
                           __hip_bfloat16* __restrict__ Kbf, float* __restrict__ bias) {
    int idx = blockIdx.x * 256 + threadIdx.x;   // 768*1024
    int p = idx >> 10, l = idx & 1023;
    if (p >= PRED) { Kbf[idx] = __float2bfloat16(0.0f); return; }  // zero pad rows
    if (l == 0) bias[p] = bs[p] + bt[p];
    float v = INV_SQRT2 * Ws[(size_t)p * 512 + (l >> 1)];   // Weff_s @ D term
    int jlo = max(0, l - 12), jhi = min(1023, l + 12);
    float acc = 0.f;
    for (int n = (jlo >> 1); n <= (jhi >> 1); n++) {
        int c = tcnt(2 * n, l) + tcnt(2 * n + 1, l);
        if (c) acc += (Wt[(size_t)p * 512 + n] - Ws[(size_t)p * 512 + n]) * (float)c;
    }
    v += acc * (INV_SQRT2 / 25.0f);
    Kbf[idx] = __float2bfloat16(v);
}

// ---------------- helpers ----------------
__device__ __forceinline__ void async_ld16(const void* g, void* l) {
    __builtin_amdgcn_global_load_lds((const __attribute__((address_space(1))) void*)g,
                                     (__attribute__((address_space(3))) void*)l, 16, 0, 0);
}

__device__ __forceinline__ short f2bf(float f) {
    __hip_bfloat16 h = __float2bfloat16(f);
    return *reinterpret_cast<short*>(&h);
}

// ---------------- xpose: x[b,l,c] f32 -> xT[b,c,l] bf16 ----------------
__global__ void __launch_bounds__(256) xpose(const float* __restrict__ x,
                                             short* __restrict__ xT) {
    __shared__ float lds[64][65];
    int t = threadIdx.x;
    int l0 = blockIdx.x * 64, c0 = blockIdx.y * 64, b = blockIdx.z;
    const float* xb = x + (size_t)b * SEQ * CH;
    int row4 = t >> 4, cq = t & 15;
#pragma unroll
    for (int i = 0; i < 4; i++) {
        int row = row4 + i * 16;
        floatx4 v = __builtin_nontemporal_load(reinterpret_cast<const floatx4*>(
            xb + (size_t)(l0 + row) * CH + c0 + cq * 4));
#pragma unroll
        for (int e = 0; e < 4; e++) lds[row][cq * 4 + e] = v[e];
    }
    __syncthreads();
    size_t outb = (size_t)b * CH * SEQ;
#pragma unroll
    for (int r = 0; r < 2; r++) {
        int u = r * 256 + t;
        int lr = u & 7, c = u >> 3;   // c in 0..63
        bf16x8 s;
#pragma unroll
        for (int e = 0; e < 8; e++) s[e] = f2bf(lds[lr * 8 + e][c]);
        *reinterpret_cast<bf16x8*>(&xT[outb + (size_t)(c0 + c) * SEQ + l0 + lr * 8]) = s;
    }
}

// ---------------- main GEMM: BM=128 BN=256 BK=64, 8 waves ----------------
// Flattened batched GEMM: A = Kbf[768][1024], B = xT viewed [32768][1024]
// (row n = b*512+c), C[n][p] -> out[b][p][c]. 3 LDS buffers (48 KB each),
// depth-2 pipeline, counted vmcnt(6), raw barriers (verified R7 structure).
// LDS layout per buffer: A slots [rowgrp16][ks][kq][lm] then B; fragment
// read byte offset = (rowgrp<<11)+(ks<<10)+(lane<<4) -> lane-linear,
// conflict-free. k-accumulation order identical to R5-R7 -> bit-identical.
__global__ void __launch_bounds__(512, 2) gemm_main_t(
    const short* __restrict__ Kbf, const short* __restrict__ xT,
    const float* __restrict__ bias, float* __restrict__ out) {
    // [buf 0..2][A 16KB | B 32KB] = 3 * 48 KB = 144 KB
    __shared__ __align__(16) short ldsbuf[3 * 24576];
    int t = threadIdx.x;
    int wave = t >> 6, lane = t & 63;
    int bid = blockIdx.x;                       // 768 blocks
    int work = (bid & 7) * 96 + (bid >> 3);     // XCD-chunked, bijective
    int mt = work % 6;                          // A panel (128 rows)
    int nt = work / 6;                          // B panel (256 n-rows), 0..127
    int wm = wave >> 2, wn = wave & 3;          // 2x4 waves of 64x64
    const short* Ag = Kbf + (size_t)mt * 128 * 1024;
    const short* Bg = xT + (size_t)nt * 256 * 1024;

    // per-thread staged-slot source offsets: slot s (16B) holds
    // row ((s>>7)<<4)+(s&15), k-offset ((s>>6)&1)*32 + ((s>>4)&3)*8
    size_t so[4];
#pragma unroll
    for (int a = 0; a < 4; a++) {
        int s = a * 512 + t;
        so[a] = (size_t)(((s >> 7) << 4) + (s & 15)) * 1024
              + ((s >> 6) & 1) * 32 + ((s >> 4) & 3) * 8;
    }

    floatx4 acc[4][4];
#pragma unroll
    for (int i = 0; i < 4; i++)
#pragma unroll
        for (int j = 0; j < 4; j++)
            acc[i][j] = (floatx4){0.f, 0.f, 0.f, 0.f};

    // stage one 128x64 A-half + 256x64 B into buffer bb at k-offset k0:
    // 2 A issues + 4 B issues per thread (16 B each), dest wave-uniform+lane*16
#define STAGE(bufidx, k0v)                                                     \
    {                                                                          \
        char* base_ = (char*)ldsbuf + (bufidx) * 49152;                        \
        _Pragma("unroll")                                                      \
        for (int a = 0; a < 2; a++)                                            \
            async_ld16(Ag + so[a] + (k0v),                                     \
                       base_ + (a * 512 + wave * 64) * 16);                    \
        _Pragma("unroll")                                                      \
        for (int a = 0; a < 4; a++)                                            \
            async_ld16(Bg + so[a] + (k0v),                                     \
                       base_ + 16384 + (a * 512 + wave * 64) * 16);            \
    }

    // prologue: stage k-tiles 0,1 into bufs 0,1
    STAGE(0, 0);
    STAGE(1, 64);

    int cur = 0, nx2 = 2;
    for (int it = 0; it < 15; ++it) {
        // outstanding: stage(it+1)'s 6 per-thread loads -> vmcnt(6) ensures
        // stage(it) fully landed (in-order completion).
        asm volatile("s_waitcnt vmcnt(6)" ::: "memory");
        __builtin_amdgcn_s_barrier();
        __builtin_amdgcn_sched_barrier(0);   // pin stage issue AFTER barrier
        if (it < 14) STAGE(nx2, (it + 2) * 64);
        const char* cb = (const char*)ldsbuf + cur * 49152;
#pragma unroll
        for (int ks = 0; ks < 2; ks++) {
            bf16x8 af[4], bf[4];
#pragma unroll
            for (int i = 0; i < 4; i++)
                af[i] = *reinterpret_cast<const bf16x8*>(
                    cb + ((wm * 4 + i) << 11) + (ks << 10) + (lane << 4));
#pragma unroll
            for (int j = 0; j < 4; j++)
                bf[j] = *reinterpret_cast<const bf16x8*>(
                    cb + 16384 + ((wn * 4 + j) << 11) + (ks << 10) + (lane << 4));
            __builtin_amdgcn_s_setprio(1);
#pragma unroll
            for (int i = 0; i < 4; i++)
#pragma unroll
                for (int j = 0; j < 4; j++)
                    acc[i][j] = __builtin_amdgcn_mfma_f32_16x16x32_bf16(af[i], bf[j], acc[i][j], 0, 0, 0);
            __builtin_amdgcn_s_setprio(0);
        }
        cur = (cur == 2) ? 0 : cur + 1;
        nx2 = (nx2 == 2) ? 0 : nx2 + 1;
    }
    // peeled last k-tile (it = 15)
    asm volatile("s_waitcnt vmcnt(0)" ::: "memory");
    __builtin_amdgcn_s_barrier();
    __builtin_amdgcn_sched_barrier(0);
    {
        const char* cb = (const char*)ldsbuf + cur * 49152;
#pragma unroll
        for (int ks = 0; ks < 2; ks++) {
            bf16x8 af[4], bf[4];
#pragma unroll
            for (int i = 0; i < 4; i++)
                af[i] = *reinterpret_cast<const bf16x8*>(
                    cb + ((wm * 4 + i) << 11) + (ks << 10) + (lane << 4));
#pragma unroll
            for (int j = 0; j < 4; j++)
                bf[j] = *reinterpret_cast<const bf16x8*>(
                    cb + 16384 + ((wn * 4 + j) << 11) + (ks << 10) + (lane << 4));
#pragma unroll
            for (int i = 0; i < 4; i++)
#pragma unroll
                for (int j = 0; j < 4; j++)
                    acc[i][j] = __builtin_amdgcn_mfma_f32_16x16x32_bf16(af[i], bf[j], acc[i][j], 0, 0, 0);
        }
    }
#undef STAGE

    // epilogue: D[row=(lane>>4)*4+r][col=lane&15], +bias, nontemporal F32 store
    int lm = lane & 15, kq = lane >> 4;
    int p0r = mt * 128 + wm * 64;
    int b   = nt >> 1;                          // n-range is 512-aligned per block
    int cb2 = (nt & 1) * 256 + wn * 64 + lm;
    size_t outb = (size_t)b * PRED * CH;
#pragma unroll
    for (int i = 0; i < 4; i++) {
#pragma unroll
        for (int r = 0; r < 4; r++) {
            int p = p0r + i * 16 + kq * 4 + r;
            if (p < PRED) {
                float bv = bias[p];
#pragma unroll
                for (int j = 0; j < 4; j++)
                    __builtin_nontemporal_store(acc[i][j][r] + bv,
                                                &out[outb + (size_t)p * CH + cb2 + j * 16]);
            }
        }
    }
}

// ---------------- fallback GEMM (verified r4 kernel, unchanged) ----------------
__global__ void __launch_bounds__(256) gemm_main(
    const short* __restrict__ Kbf, const float* __restrict__ x,
    const float* __restrict__ bias, float* __restrict__ out) {
    __shared__ __align__(16) short ldsA[128 * 32];   // 8 KB
    int t = threadIdx.x;
    int wave = t >> 6, lane = t & 63;
    int mt = blockIdx.x % 6, nt = blockIdx.x / 6;
    int b  = blockIdx.y;
    int wm = wave >> 1, wn = wave & 1;
    const short* Ag = Kbf + (size_t)mt * 128 * 1024;
    const float* xb = x + (size_t)b * SEQ * CH;
    int lm = lane & 15, kq = lane >> 4;
    int cj[4];
    for (int j = 0; j < 4; j++) cj[j] = nt * 128 + wn * 64 + j * 16 + lm;

    floatx4 acc[4][4];
    for (int i = 0; i < 4; i++)
        for (int j = 0; j < 4; j++)
            acc[i][j] = (floatx4){0.f, 0.f, 0.f, 0.f};

    for (int k0 = 0; k0 < 1024; k0 += 32) {
        for (int rdi = 0; rdi < 2; rdi++) {
            int q = rdi * 256 + t;
            int row = q >> 2, ko = (q & 3) * 8;
            async_ld16(Ag + (size_t)row * 1024 + k0 + ko,
                       (char*)ldsA + rdi * 4096 + wave * 1024);
        }
        bf16x8 bfrag[4];
        int krow = k0 + kq * 8;
#pragma unroll
        for (int j = 0; j < 4; j++) {
            const float* xc = xb + (size_t)krow * CH + cj[j];
            bf16x8 bv;
#pragma unroll
            for (int i = 0; i < 8; i++) bv[i] = f2bf(xc[(size_t)i * CH]);
            bfrag[j] = bv;
        }
        __syncthreads();
        bf16x8 af[4];
        for (int i = 0; i < 4; i++)
            af[i] = *(const bf16x8*)&ldsA[(wm * 64 + i * 16 + lm) * 32 + kq * 8];
        for (int i = 0; i < 4; i++)
            for (int j = 0; j < 4; j++)
                acc[i][j] = __builtin_amdgcn_mfma_f32_16x16x32_bf16(af[i], bfrag[j], acc[i][j], 0, 0, 0);
        __syncthreads();
    }

    int p0 = mt * 128 + wm * 64;
    size_t outb = (size_t)b * PRED * CH;
    for (int i = 0; i < 4; i++) {
        for (int r = 0; r < 4; r++) {
            int p = p0 + i * 16 + kq * 4 + r;
            if (p < PRED) {
                float bv = bias[p];
                for (int j = 0; j < 4; j++) {
                    out[outb + (size_t)p * CH + cj[j]] = acc[i][j][r] + bv;
                }
            }
        }
    }
}

extern "C" void kernel_launch(void* const* d_in, const int* in_sizes, int n_in,
                              void* d_out, int out_size, void* d_ws, size_t ws_size,
                              hipStream_t stream) {
    // size-based remap (robust to order); fallback to dict order
    const float* xp = nullptr; const float* wp[2] = {nullptr, nullptr};
    const float* bp[2] = {nullptr, nullptr};
    int wn = 0, bn = 0;
    for (int i = 0; i < n_in; i++) {
        if (in_sizes[i] == 33554432) xp = (const float*)d_in[i];
        else if (in_sizes[i] == 368640 && wn < 2) wp[wn++] = (const float*)d_in[i];
        else if (in_sizes[i] == 720 && bn < 2) bp[bn++] = (const float*)d_in[i];
    }
    if (!xp || wn != 2 || bn != 2) {
        xp = (const float*)d_in[0]; wp[0] = (const float*)d_in[1];
        bp[0] = (const float*)d_in[2]; wp[1] = (const float*)d_in[3];
        bp[1] = (const float*)d_in[4];
    }
    float* out = (float*)d_out;   // F32 output

    char* ws = (char*)d_ws;
    __hip_bfloat16* Kbf = (__hip_bfloat16*)(ws + KBF_OFF);
    float* bias  = (float*)(ws + BIAS_OFF);
    float* WeffS = (float*)(ws + WEFFS_OFF);
    float* WeffT = (float*)(ws + WEFFT_OFF);
    short* xT    = (short*)(ws + XT_OFF);

    bool big = (ws_size >= (size_t)WS_NEED);

    if (big) xpose<<<dim3(16, 8, 64), 256, 0, stream>>>(xp, xT);
    build_weff<<<dim3(8, 12, 2), 256, 0, stream>>>(wp[0], wp[1], WeffS, WeffT);
    build_kmat<<<3072, 256, 0, stream>>>(WeffS, WeffT, bp[0], bp[1], Kbf, bias);
    if (big)
        gemm_main_t<<<768, 512, 0, stream>>>((const short*)Kbf, (const short*)xT, bias, out);
    else
        gemm_main<<<dim3(24, 64), 256, 0, stream>>>((const short*)Kbf, xp, bias, out);
}